// Round 4
// baseline (5525.074 us; speedup 1.0000x reference)
//
#include <hip/hip_runtime.h>
#include <math.h>

// Problem constants
#define BB 32
#define TT 512
#define II 96
#define HH 256
#define MM 6
#define OUTD 64

// d_out region offsets (floats)
#define O_HSEQ  1048576
#define O_AIN   26214400
#define O_ACM   51380224
#define O_ATTN  76546048

// ws layout (floats)
#define WS_WEFF 0
#define WS_UT   49152
#define WS_WQT  73728
#define WS_WKT  98304
#define WS_VC   122880
#define WS_QK   221184
#define WS_FLAG 233472
#define WS_COOP_FLOATS 233984

// lgkm-only barrier: orders LDS producer->consumer without draining vmcnt
// (global stores keep flowing; "memory" clobber stops compiler reordering)
#define LBAR() asm volatile("s_waitcnt lgkmcnt(0)\n\ts_barrier" ::: "memory")

// ---------------------------------------------------------------------------
// K0: build Weff[m] = W_in[m] @ W_ip[m]  (m=0..3) and pre-transpose U, W_Q, W_K
// ---------------------------------------------------------------------------
__global__ __launch_bounds__(256) void rim_weff(
    const float* __restrict__ Wtask, const float* __restrict__ Wsens,
    const float* __restrict__ Wip,
    const float* __restrict__ U, const float* __restrict__ WQ, const float* __restrict__ WK,
    float* __restrict__ Weff, float* __restrict__ Ut, float* __restrict__ WQt, float* __restrict__ WKt)
{
  __shared__ float row[256];
  const int bidx = blockIdx.x;
  const int tid = threadIdx.x;
  if (bidx < 192) {
    int m, i;
    if (bidx < 32)       { m = 0; i = bidx; }
    else if (bidx < 64)  { m = 1; i = bidx - 32; }
    else if (bidx < 128) { m = 2; i = bidx - 64; }
    else                 { m = 3; i = bidx - 128; }
    row[tid] = (m < 2) ? Wtask[(m * 32 + i) * 256 + tid]
                       : Wsens[((m - 2) * 64 + i) * 256 + tid];
    __syncthreads();
    float acc = 0.f;
    const float* wip = Wip + m * 65536 + tid;
    #pragma unroll 8
    for (int j = 0; j < 256; ++j) acc += row[j] * wip[j * 256];
    const int base = (m == 0) ? 0 : (m == 1) ? 8192 : (m == 2) ? 16384 : 32768;
    Weff[base + i * 256 + tid] = acc;
  } else {
    const int p = bidx - 192;       // 0..95
    const int m = p >> 4, r = p & 15;
    Ut [(m * 16 + r) * 256 + tid] = U [m * 4096 + tid * 16 + r];
    WQt[(m * 16 + r) * 256 + tid] = WQ[m * 4096 + tid * 16 + r];
    WKt[(m * 16 + r) * 256 + tid] = WK[m * 4096 + tid * 16 + r];
  }
}

// ---------------------------------------------------------------------------
// K1: parallel Ain_seq output (independent of the recurrence)
// ---------------------------------------------------------------------------
__global__ __launch_bounds__(256) void rim_pre(
    const float* __restrict__ x,
    const float* __restrict__ Wtask, const float* __restrict__ Wsens,
    float* __restrict__ Ain)
{
  __shared__ float xr[16][96];
  const int tid = threadIdx.x;
  const int rb0 = blockIdx.x * 16;
  for (int idx = tid; idx < 16 * 96; idx += 256) {
    int r = idx / 96, c = idx % 96;
    int rb = rb0 + r; int t = rb >> 5, b = rb & 31;
    xr[r][c] = x[(b * TT + t) * II + c];
  }
  __syncthreads();
  const int h = tid;
  float acc[16];

  for (int m = 0; m < 4; ++m) {
    const int cnt  = (m < 2) ? 32 : 64;
    const int xoff = (m < 2) ? 64 : 0;
    const float* W = (m < 2) ? (Wtask + m * 32 * 256) : (Wsens + (m - 2) * 64 * 256);
    #pragma unroll
    for (int r = 0; r < 16; ++r) acc[r] = 0.f;
    for (int i = 0; i < cnt; ++i) {
      float w = W[i * 256 + h];
      #pragma unroll
      for (int r = 0; r < 16; ++r) acc[r] += xr[r][xoff + i] * w;
    }
    #pragma unroll
    for (int r = 0; r < 16; ++r) {
      int rb = rb0 + r; int t = rb >> 5, b = rb & 31;
      Ain[((t * 32 + b) * 6 + m) * 256 + h] = acc[r];
    }
  }
  #pragma unroll
  for (int r = 0; r < 16; ++r) {
    int rb = rb0 + r; int t = rb >> 5, b = rb & 31;
    Ain[((t * 32 + b) * 6 + 4) * 256 + h] = 0.f;
    Ain[((t * 32 + b) * 6 + 5) * 256 + h] = 0.f;
  }
}

// ---------------------------------------------------------------------------
// K2: cooperative recurrence, wave-specialized. 192 blocks = (m*32+b), 512 thr.
//  waves 0-3: Vc full-dot (W_V column in 256 VGPRs), publish
//  wave  4  : Q/K compute + publish + seqQK (own drain hidden under Vc)
//  waves 5-6: input-projection for step t+1 (off critical path)
//  wave  7  : poll peers' seqQK + load Q/K; attention during seqVc poll
// All mailbox traffic = cache-bypassing SYSTEM-scope relaxed atomics (no fences).
// ---------------------------------------------------------------------------
__global__ __launch_bounds__(512, 1) void rim_step(
    const float* __restrict__ x,
    const float* __restrict__ Vr, const float* __restrict__ WV,
    const float* __restrict__ bip, const float* __restrict__ cbias,
    const float* __restrict__ UtW, const float* __restrict__ WQtW,
    const float* __restrict__ WKtW, const float* __restrict__ WeffW,
    float* __restrict__ VcG, float* __restrict__ QKG,
    unsigned int* __restrict__ seqG,
    float* __restrict__ Hseq, float* __restrict__ Acm, float* __restrict__ attnO)
{
  __shared__ __align__(16) float Hl[256];
  __shared__ __align__(16) float Hin[256];
  __shared__ float biasl[256];
  __shared__ float Utl[16][257];    // +1 pad: kills bank conflicts
  __shared__ float Vrl[16][257];
  __shared__ float WQtl[16][257];
  __shared__ float WKtl[16][257];
  __shared__ float Weffl[64][256];
  __shared__ float inpl[2][256];
  __shared__ float xl[2][96];
  __shared__ float tmpUr[16];
  __shared__ float attnl[40];
  __shared__ float qkl[192];

  const int bid = blockIdx.x;
  const int m = bid >> 5;        // 0..5
  const int b = bid & 31;        // 0..31
  const int tid = threadIdx.x;
  const int w64 = tid >> 6, lane = tid & 63;
  const int g32 = tid >> 5, l32 = tid & 31;

  const int base = (m == 0) ? 0 : (m == 1) ? 8192 : (m == 2) ? 16384 : 32768;
  const int cnt  = (m < 2) ? 32 : 64;
  const int xoff = (m < 2) ? 64 : 0;

  // ---- init: stage per-module weights into LDS ----
  for (int i = tid; i < 4096; i += 512) {
    int r = i >> 8, c = i & 255;
    Utl [r][c] = UtW [m * 4096 + i];
    Vrl [r][c] = Vr  [m * 4096 + i];
    WQtl[r][c] = WQtW[m * 4096 + i];
    WKtl[r][c] = WKtW[m * 4096 + i];
  }
  if (m < 4)
    for (int i = tid; i < cnt * 256; i += 512)
      ((float*)Weffl)[i] = WeffW[base + i];
  if (tid < 256) {
    biasl[tid] = bip[m * 256 + tid] + cbias[m * 256 + tid];
    Hl[tid] = 0.f;
  }
  float xreg = 0.f;
  if (m < 4 && tid < 96) {
    xl[0][tid] = x[((size_t)b * TT + 0) * II + tid];
    xreg       = x[((size_t)b * TT + 1) * II + tid];
  }
  // W_V full column in registers: w[j] = WV[m][j][tid]  (tid<256)
  float w[256];
  if (tid < 256) {
    #pragma unroll
    for (int j = 0; j < 256; ++j)
      w[j] = WV[((size_t)(m * 256 + j)) * 256 + tid];
  }
  __syncthreads();
  // inp for t=0
  if (m < 4 && tid < 256) {
    float a = 0.f;
    for (int i = 0; i < cnt; ++i) a += xl[0][xoff + i] * Weffl[i][tid];
    inpl[0][tid] = a;
  }
  __syncthreads();

  for (int t = 0; t < TT; ++t) {
    const int buf = t & 1;
    const int xb6 = (buf * 32 + b) * 6;

    // stage x_{t+1} from prefetch reg; issue prefetch for x_{t+2}
    if (m < 4 && tid < 96) {
      xl[(t + 1) & 1][tid] = xreg;
      xreg = (t + 2 < TT) ? x[((size_t)b * TT + t + 2) * II + tid] : 0.f;
    }

    // ---- tmpUr[r] = sum_h Hl[h] * U[m][h][r]  (16 groups of 32 lanes) ----
    {
      float s = 0.f;
      const float* up = &Utl[g32][0];
      #pragma unroll
      for (int h = l32; h < 256; h += 32) s += Hl[h] * up[h];
      #pragma unroll
      for (int off = 16; off > 0; off >>= 1) s += __shfl_down(s, off, 32);
      if (l32 == 0) tmpUr[g32] = s;
    }
    LBAR();  // B1

    // ---- Hin = tanh(inp + rec + bias) ----
    if (tid < 256) {
      float rec = 0.f;
      #pragma unroll
      for (int r = 0; r < 16; ++r) rec += tmpUr[r] * Vrl[r][tid];
      float inp = (m < 4) ? inpl[buf][tid] : 0.f;
      Hin[tid] = tanhf(inp + rec + biasl[tid]);
    }
    LBAR();  // B2

    // ---- wave-specialized phase ----
    float acc = 0.f;
    if (w64 < 4) {
      // Vc full dot: uniform-broadcast LDS reads + 256 reg-FMA
      const float4* h4 = (const float4*)Hin;
      #pragma unroll
      for (int q = 0; q < 64; ++q) {
        float4 hv = h4[q];
        acc += hv.x * w[4 * q] + hv.y * w[4 * q + 1]
             + hv.z * w[4 * q + 2] + hv.w * w[4 * q + 3];
      }
      __hip_atomic_store(&VcG[(xb6 + m) * 256 + tid], acc,
                         __ATOMIC_RELAXED, __HIP_MEMORY_SCOPE_SYSTEM);
    } else if (w64 == 4) {
      // Q/K: 32 outputs, 2 lanes each; publish early + seqQK
      const int o = lane >> 1, hf = lane & 1, h0 = hf * 128;
      const float* wp = (o < 16) ? &WQtl[o][0] : &WKtl[o - 16][0];
      float s = 0.f;
      #pragma unroll
      for (int j = 0; j < 128; ++j) s += Hin[h0 + j] * wp[h0 + j];
      s += __shfl_down(s, 1, 64);
      if (hf == 0)
        __hip_atomic_store(&QKG[(buf * 32 + b) * 192 + m * 32 + o], s,
                           __ATOMIC_RELAXED, __HIP_MEMORY_SCOPE_SYSTEM);
      asm volatile("s_waitcnt vmcnt(0)" ::: "memory");
      if (lane == 0)
        __hip_atomic_store(&seqG[b * 16 + m], (unsigned)(t + 1),
                           __ATOMIC_RELAXED, __HIP_MEMORY_SCOPE_SYSTEM);
    } else if (w64 == 7) {
      // poll all 6 seqQK, then pull 192 Q/K floats into LDS
      if (lane < 6) {
        while (__hip_atomic_load(&seqG[b * 16 + lane],
                                 __ATOMIC_RELAXED, __HIP_MEMORY_SCOPE_SYSTEM)
               < (unsigned)(t + 1)) {}
      }
      const int qb = (buf * 32 + b) * 192;
      float q0 = __hip_atomic_load(&QKG[qb + lane],       __ATOMIC_RELAXED, __HIP_MEMORY_SCOPE_SYSTEM);
      float q1 = __hip_atomic_load(&QKG[qb + 64 + lane],  __ATOMIC_RELAXED, __HIP_MEMORY_SCOPE_SYSTEM);
      float q2 = __hip_atomic_load(&QKG[qb + 128 + lane], __ATOMIC_RELAXED, __HIP_MEMORY_SCOPE_SYSTEM);
      qkl[lane] = q0; qkl[64 + lane] = q1; qkl[128 + lane] = q2;
    } else {
      // waves 5,6: input projection for t+1 (2 h's per lane)
      if (m < 4) {
        const int h0 = (tid - 320) * 2;
        const int nb = (t + 1) & 1;
        float a0 = 0.f, a1 = 0.f;
        for (int i = 0; i < cnt; ++i) {
          float xv = xl[nb][xoff + i];
          a0 += xv * Weffl[i][h0];
          a1 += xv * Weffl[i][h0 + 1];
        }
        inpl[nb][h0] = a0; inpl[nb][h0 + 1] = a1;
      }
    }
    __syncthreads();  // B3 — the one full (vmcnt-draining) barrier: Vc is at IF

    if (tid == 0)
      __hip_atomic_store(&seqG[b * 16 + 8 + m], (unsigned)(t + 1),
                         __ATOMIC_RELAXED, __HIP_MEMORY_SCOPE_SYSTEM);
    // attention (wave 7) overlapped with seqVc poll (wave 0)
    if (w64 == 7 && lane < 6) {
      float sc[6]; float mx = -1e30f;
      #pragma unroll
      for (int n = 0; n < 6; ++n) {
        float s = 0.f;
        #pragma unroll
        for (int k = 0; k < 16; ++k) s += qkl[lane * 32 + k] * qkl[n * 32 + 16 + k];
        sc[n] = s * 0.25f; mx = fmaxf(mx, sc[n]);
      }
      float sm = 0.f;
      #pragma unroll
      for (int n = 0; n < 6; ++n) { sc[n] = expf(sc[n] - mx); sm += sc[n]; }
      float inv = 1.f / sm;
      #pragma unroll
      for (int n = 0; n < 6; ++n) {
        float a = sc[n] * inv;
        attnl[lane * 6 + n] = a;
        if (m == 0) attnO[((size_t)t * 32 + b) * 36 + lane * 6 + n] = a;
      }
    }
    if (w64 == 0 && lane < 6) {
      while (__hip_atomic_load(&seqG[b * 16 + 8 + lane],
                               __ATOMIC_RELAXED, __HIP_MEMORY_SCOPE_SYSTEM)
             < (unsigned)(t + 1)) {}
    }
    LBAR();  // B4 — no drain; peers' Vc known-visible via poll

    // ---- A_comm + H_new (own module only) ----
    if (tid < 256) {
      float vcv[6];
      #pragma unroll
      for (int mm = 0; mm < 6; ++mm)
        vcv[mm] = (mm == m) ? acc
                 : __hip_atomic_load(&VcG[(xb6 + mm) * 256 + tid],
                                     __ATOMIC_RELAXED, __HIP_MEMORY_SCOPE_SYSTEM);
      float ac = 0.f;
      #pragma unroll
      for (int mm = 0; mm < 6; ++mm) ac += attnl[mm * 6 + m] * vcv[mm];
      float hn = Hin[tid] + ac;
      Hl[tid] = hn;
      size_t gi = (((size_t)t * 32 + b) * 6 + m) * 256 + tid;
      Hseq[gi] = hn;
      Acm[gi]  = ac;
    }
    LBAR();  // B8 — Hl ready; Hseq/Acm drain off critical path
  }
}

// ---------------------------------------------------------------------------
// K3: out[b,t,:] = concat(Hseq[t,b,4,:], Hseq[t,b,5,:]) @ W_out + b_out
// ---------------------------------------------------------------------------
__global__ __launch_bounds__(256) void rim_out(
    const float* __restrict__ Hseq, const float* __restrict__ Wout,
    const float* __restrict__ bout, float* __restrict__ out0)
{
  __shared__ float hrow[4][512];
  const int tid = threadIdx.x;
  const int row0 = blockIdx.x * 4;
  for (int i = tid; i < 4 * 512; i += 256) {
    int r = i >> 9, j = i & 511;
    int rb = row0 + r; int b = rb >> 9, t = rb & 511;
    hrow[r][j] = Hseq[((size_t)(t * 32 + b) * 6 + 4 + (j >> 8)) * 256 + (j & 255)];
  }
  __syncthreads();
  const int r = tid >> 6, o = tid & 63;
  const int rb = row0 + r;
  float s = bout[o];
  const float* hp = hrow[r];
  const float* wp = Wout + o;
  #pragma unroll 8
  for (int j = 0; j < 512; ++j) s += hp[j] * wp[(size_t)j * 64];
  out0[(size_t)rb * 64 + o] = s;
}

// ---------------------------------------------------------------------------
// Fallback (round-1 monolithic loop, one block per batch)
// ---------------------------------------------------------------------------
__global__ __launch_bounds__(512) void rim_loop(
    const float* __restrict__ x,
    const float* __restrict__ Vr, const float* __restrict__ WV,
    const float* __restrict__ Wout, const float* __restrict__ bout,
    const float* __restrict__ bip, const float* __restrict__ cbias,
    const float* __restrict__ Ut, const float* __restrict__ WQt, const float* __restrict__ WKt,
    const float* __restrict__ Weff,
    float* __restrict__ out0, float* __restrict__ Hseq,
    float* __restrict__ Acm, float* __restrict__ attnO)
{
  __shared__ float Hl[6][256];
  __shared__ float Hin[6][256];
  __shared__ float biasl[6][256];
  __shared__ float Vcp[2][6][256];
  __shared__ float tmpUr[6][16];
  __shared__ float Qc[6][16], Kc[6][16];
  __shared__ float attnl[36];
  __shared__ float pout[8][64];
  __shared__ float xl[96];
  __shared__ float inpl[4][256];

  const int b = blockIdx.x;
  const int tid = threadIdx.x;
  const int wid = tid >> 5, lane = tid & 31;

  for (int i = tid; i < 1536; i += 512) {
    int m = i >> 8, h = i & 255;
    biasl[m][h] = bip[i] + cbias[i];
    Hl[m][h] = 0.f;
  }
  __syncthreads();

  for (int t = 0; t < TT; ++t) {
    if (tid < 96) xl[tid] = x[(b * TT + t) * II + tid];
    __syncthreads();
    for (int mh = tid; mh < 1024; mh += 512) {
      int m = mh >> 8, h = mh & 255;
      const int base = (m == 0) ? 0 : (m == 1) ? 8192 : (m == 2) ? 16384 : 32768;
      const int cnt  = (m < 2) ? 32 : 64;
      const int xoff = (m < 2) ? 64 : 0;
      float a = 0.f;
      for (int i = 0; i < cnt; ++i) a += xl[xoff + i] * Weff[base + i * 256 + h];
      inpl[m][h] = a;
    }

    for (int pq = wid; pq < 96; pq += 16) {
      int m = pq >> 4, r = pq & 15;
      const float* up = Ut + (m * 16 + r) * 256;
      float s = 0.f;
      #pragma unroll
      for (int h = lane; h < 256; h += 32) s += Hl[m][h] * up[h];
      #pragma unroll
      for (int off = 16; off > 0; off >>= 1) s += __shfl_down(s, off, 32);
      if (lane == 0) tmpUr[m][r] = s;
    }
    __syncthreads();

    for (int mh = tid; mh < 1536; mh += 512) {
      int m = mh >> 8, h = mh & 255;
      float rec = 0.f;
      const float* vp = Vr + m * 4096 + h;
      #pragma unroll
      for (int r = 0; r < 16; ++r) rec += tmpUr[m][r] * vp[r * 256];
      float pre = (m < 4) ? inpl[m][h] : 0.f;
      Hin[m][h] = tanhf(pre + rec + biasl[m][h]);
    }
    __syncthreads();

    for (int pq = wid; pq < 192; pq += 16) {
      int q = pq % 96;
      int m = q >> 4, k = q & 15;
      const float* wp = ((pq < 96) ? WQt : WKt) + (m * 16 + k) * 256;
      float s = 0.f;
      #pragma unroll
      for (int h = lane; h < 256; h += 32) s += Hin[m][h] * wp[h];
      #pragma unroll
      for (int off = 16; off > 0; off >>= 1) s += __shfl_down(s, off, 32);
      if (lane == 0) { if (pq < 96) Qc[m][k] = s; else Kc[m][k] = s; }
    }

    {
      const int h_out = tid & 255, half = tid >> 8;
      for (int m = 0; m < 6; ++m) {
        const float* wv = WV + ((size_t)(m * 256 + half * 128)) * 256 + h_out;
        const float* hv = &Hin[m][half * 128];
        float s = 0.f;
        #pragma unroll 8
        for (int j = 0; j < 128; ++j) s += hv[j] * wv[(size_t)j * 256];
        Vcp[half][m][h_out] = s;
      }
    }
    __syncthreads();

    if (tid < 36) {
      int m = tid / 6, n = tid % 6;
      float s = 0.f;
      #pragma unroll
      for (int k = 0; k < 16; ++k) s += Qc[m][k] * Kc[n][k];
      attnl[tid] = s * 0.25f;
    }
    __syncthreads();
    if (tid < 6) {
      int m = tid;
      float mx = -1e30f;
      #pragma unroll
      for (int n = 0; n < 6; ++n) mx = fmaxf(mx, attnl[m * 6 + n]);
      float e[6], sm = 0.f;
      #pragma unroll
      for (int n = 0; n < 6; ++n) { e[n] = expf(attnl[m * 6 + n] - mx); sm += e[n]; }
      float inv = 1.f / sm;
      #pragma unroll
      for (int n = 0; n < 6; ++n) attnl[m * 6 + n] = e[n] * inv;
    }
    __syncthreads();
    if (tid < 36) attnO[(size_t)(t * 32 + b) * 36 + tid] = attnl[tid];

    for (int mh = tid; mh < 1536; mh += 512) {
      int n = mh >> 8, h = mh & 255;
      float ac = 0.f;
      #pragma unroll
      for (int m = 0; m < 6; ++m)
        ac += attnl[m * 6 + n] * (Vcp[0][m][h] + Vcp[1][m][h]);
      float hn = Hin[n][h] + ac;
      Hl[n][h] = hn;
      size_t gi = ((size_t)(t * 32 + b) * 6 + n) * 256 + h;
      Hseq[gi] = hn;
      Acm[gi]  = ac;
    }
    __syncthreads();

    {
      const int o = tid & 63, js = tid >> 6;
      const float* hp = &Hl[4][0];
      const float* wp = Wout + (size_t)(js * 64) * 64 + o;
      float s = 0.f;
      #pragma unroll 8
      for (int jj = 0; jj < 64; ++jj) s += hp[js * 64 + jj] * wp[(size_t)jj * 64];
      pout[js][o] = s;
    }
    __syncthreads();
    if (tid < 64) {
      float s = bout[tid];
      #pragma unroll
      for (int js = 0; js < 8; ++js) s += pout[js][tid];
      out0[(size_t)(b * TT + t) * 64 + tid] = s;
    }
  }
}

// ---------------------------------------------------------------------------
extern "C" void kernel_launch(void* const* d_in, const int* in_sizes, int n_in,
                              void* d_out, int out_size, void* d_ws, size_t ws_size,
                              hipStream_t stream) {
  const float* x    = (const float*)d_in[0];
  const float* W_ip = (const float*)d_in[1];
  const float* b_ip = (const float*)d_in[2];
  const float* U    = (const float*)d_in[3];
  const float* Vr   = (const float*)d_in[4];
  const float* cb   = (const float*)d_in[5];
  const float* Wt   = (const float*)d_in[6];
  const float* Wsn  = (const float*)d_in[7];
  const float* WQ   = (const float*)d_in[8];
  const float* WK   = (const float*)d_in[9];
  const float* WV   = (const float*)d_in[10];
  const float* Wo   = (const float*)d_in[11];
  const float* bo   = (const float*)d_in[12];

  float* out  = (float*)d_out;
  float* Hseq = out + O_HSEQ;
  float* Ain  = out + O_AIN;
  float* Acm  = out + O_ACM;
  float* attn = out + O_ATTN;

  float* ws   = (float*)d_ws;
  float* Weff = ws + WS_WEFF;
  float* Ut   = ws + WS_UT;
  float* WQt  = ws + WS_WQT;
  float* WKt  = ws + WS_WKT;

  hipLaunchKernelGGL(rim_weff, dim3(288), dim3(256), 0, stream,
                     Wt, Wsn, W_ip, U, WQ, WK, Weff, Ut, WQt, WKt);
  hipLaunchKernelGGL(rim_pre, dim3(1024), dim3(256), 0, stream,
                     x, Wt, Wsn, Ain);

  if (ws_size >= (size_t)WS_COOP_FLOATS * sizeof(float)) {
    float* VcG = ws + WS_VC;
    float* QKG = ws + WS_QK;
    unsigned int* seqG = (unsigned int*)(ws + WS_FLAG);
    hipMemsetAsync((void*)seqG, 0, 512 * sizeof(unsigned int), stream);

    void* args[] = { (void*)&x, (void*)&Vr, (void*)&WV, (void*)&b_ip, (void*)&cb,
                     (void*)&Ut, (void*)&WQt, (void*)&WKt, (void*)&Weff,
                     (void*)&VcG, (void*)&QKG, (void*)&seqG,
                     (void*)&Hseq, (void*)&Acm, (void*)&attn };
    hipLaunchCooperativeKernel((void*)rim_step, dim3(192), dim3(512), args, 0, stream);

    hipLaunchKernelGGL(rim_out, dim3(4096), dim3(256), 0, stream,
                       Hseq, Wo, bo, out);
  } else {
    hipLaunchKernelGGL(rim_loop, dim3(32), dim3(512), 0, stream,
                       x, Vr, WV, Wo, bo, b_ip, cb, Ut, WQt, WKt, Weff,
                       out, Hseq, Acm, attn);
  }
}

// Round 5
// 2576.820 us; speedup vs baseline: 2.1441x; 2.1441x over previous
//
#include <hip/hip_runtime.h>
#include <math.h>

// Problem constants
#define BB 32
#define TT 512
#define II 96
#define HH 256
#define MM 6
#define OUTD 64

// d_out region offsets (floats)
#define O_HSEQ  1048576
#define O_AIN   26214400
#define O_ACM   51380224
#define O_ATTN  76546048

// ws layout (floats)
#define WS_WEFF 0
#define WS_UT   49152
#define WS_WQT  73728
#define WS_WKT  98304
#define WS_VCH  122880              /* 2*32*12*256 = 196608 */
#define WS_QK   319488              /* 2*32*192   = 12288  */
#define WS_FLAG 331776              /* 512 */
#define WS_COOP_FLOATS 332288

// lgkm-only barrier: orders LDS producer->consumer without draining vmcnt
#define LBAR() asm volatile("s_waitcnt lgkmcnt(0)\n\ts_barrier" ::: "memory")

// ---------------------------------------------------------------------------
// K0: build Weff[m] = W_in[m] @ W_ip[m]  (m=0..3) and pre-transpose U, W_Q, W_K
// ---------------------------------------------------------------------------
__global__ __launch_bounds__(256) void rim_weff(
    const float* __restrict__ Wtask, const float* __restrict__ Wsens,
    const float* __restrict__ Wip,
    const float* __restrict__ U, const float* __restrict__ WQ, const float* __restrict__ WK,
    float* __restrict__ Weff, float* __restrict__ Ut, float* __restrict__ WQt, float* __restrict__ WKt)
{
  __shared__ float row[256];
  const int bidx = blockIdx.x;
  const int tid = threadIdx.x;
  if (bidx < 192) {
    int m, i;
    if (bidx < 32)       { m = 0; i = bidx; }
    else if (bidx < 64)  { m = 1; i = bidx - 32; }
    else if (bidx < 128) { m = 2; i = bidx - 64; }
    else                 { m = 3; i = bidx - 128; }
    row[tid] = (m < 2) ? Wtask[(m * 32 + i) * 256 + tid]
                       : Wsens[((m - 2) * 64 + i) * 256 + tid];
    __syncthreads();
    float acc = 0.f;
    const float* wip = Wip + m * 65536 + tid;
    #pragma unroll 8
    for (int j = 0; j < 256; ++j) acc += row[j] * wip[j * 256];
    const int base = (m == 0) ? 0 : (m == 1) ? 8192 : (m == 2) ? 16384 : 32768;
    Weff[base + i * 256 + tid] = acc;
  } else {
    const int p = bidx - 192;       // 0..95
    const int m = p >> 4, r = p & 15;
    Ut [(m * 16 + r) * 256 + tid] = U [m * 4096 + tid * 16 + r];
    WQt[(m * 16 + r) * 256 + tid] = WQ[m * 4096 + tid * 16 + r];
    WKt[(m * 16 + r) * 256 + tid] = WK[m * 4096 + tid * 16 + r];
  }
}

// ---------------------------------------------------------------------------
// K1: parallel Ain_seq output (independent of the recurrence)
// ---------------------------------------------------------------------------
__global__ __launch_bounds__(256) void rim_pre(
    const float* __restrict__ x,
    const float* __restrict__ Wtask, const float* __restrict__ Wsens,
    float* __restrict__ Ain)
{
  __shared__ float xr[16][96];
  const int tid = threadIdx.x;
  const int rb0 = blockIdx.x * 16;
  for (int idx = tid; idx < 16 * 96; idx += 256) {
    int r = idx / 96, c = idx % 96;
    int rb = rb0 + r; int t = rb >> 5, b = rb & 31;
    xr[r][c] = x[(b * TT + t) * II + c];
  }
  __syncthreads();
  const int h = tid;
  float acc[16];

  for (int m = 0; m < 4; ++m) {
    const int cnt  = (m < 2) ? 32 : 64;
    const int xoff = (m < 2) ? 64 : 0;
    const float* W = (m < 2) ? (Wtask + m * 32 * 256) : (Wsens + (m - 2) * 64 * 256);
    #pragma unroll
    for (int r = 0; r < 16; ++r) acc[r] = 0.f;
    for (int i = 0; i < cnt; ++i) {
      float w = W[i * 256 + h];
      #pragma unroll
      for (int r = 0; r < 16; ++r) acc[r] += xr[r][xoff + i] * w;
    }
    #pragma unroll
    for (int r = 0; r < 16; ++r) {
      int rb = rb0 + r; int t = rb >> 5, b = rb & 31;
      Ain[((t * 32 + b) * 6 + m) * 256 + h] = acc[r];
    }
  }
  #pragma unroll
  for (int r = 0; r < 16; ++r) {
    int rb = rb0 + r; int t = rb >> 5, b = rb & 31;
    Ain[((t * 32 + b) * 6 + 4) * 256 + h] = 0.f;
    Ain[((t * 32 + b) * 6 + 5) * 256 + h] = 0.f;
  }
}

// ---------------------------------------------------------------------------
// K2: cooperative recurrence. 192 blocks = (m*32+b), 512 threads.
// W_V half-column per thread (w[128], no spill). Seq-word signaling (no RMW).
// Vc halves published straight from registers. inp(t+1) overlapped with poll.
// All mailbox traffic = cache-bypassing SYSTEM-scope relaxed atomics.
// ---------------------------------------------------------------------------
__global__ __launch_bounds__(512, 2) void rim_step(
    const float* __restrict__ x,
    const float* __restrict__ Vr, const float* __restrict__ WV,
    const float* __restrict__ bip, const float* __restrict__ cbias,
    const float* __restrict__ UtW, const float* __restrict__ WQtW,
    const float* __restrict__ WKtW, const float* __restrict__ WeffW,
    float* __restrict__ VcHG, float* __restrict__ QKG,
    unsigned int* __restrict__ seqG,
    float* __restrict__ Hseq, float* __restrict__ Acm, float* __restrict__ attnO)
{
  __shared__ __align__(16) float Hl[256];
  __shared__ __align__(16) float Hin[256];
  __shared__ float biasl[256];
  __shared__ float Utl[16][257];    // +1 pad
  __shared__ float Vrl[16][257];
  __shared__ float WQtl[16][257];
  __shared__ float WKtl[16][257];
  __shared__ float Weffl[64][256];
  __shared__ float inpl[2][256];
  __shared__ float xl[2][96];
  __shared__ float Vcp1[256];       // p=1 half of own Vc
  __shared__ float tmpUr[16];
  __shared__ float attnl[40];
  __shared__ float qkl[192];

  const int bid = blockIdx.x;
  const int m = bid >> 5;        // 0..5
  const int b = bid & 31;        // 0..31
  const int tid = threadIdx.x;
  const int g32 = tid >> 5, l32 = tid & 31;
  const int h_out = tid & 255, p = tid >> 8;
  const int g16 = tid >> 4, l16 = tid & 15;
  const int w64 = tid >> 6, lane = tid & 63;

  const int base = (m == 0) ? 0 : (m == 1) ? 8192 : (m == 2) ? 16384 : 32768;
  const int cnt  = (m < 2) ? 32 : 64;
  const int xoff = (m < 2) ? 64 : 0;

  // ---- init: stage per-module weights into LDS ----
  for (int i = tid; i < 4096; i += 512) {
    int r = i >> 8, c = i & 255;
    Utl [r][c] = UtW [m * 4096 + i];
    Vrl [r][c] = Vr  [m * 4096 + i];
    WQtl[r][c] = WQtW[m * 4096 + i];
    WKtl[r][c] = WKtW[m * 4096 + i];
  }
  if (m < 4)
    for (int i = tid; i < cnt * 256; i += 512)
      ((float*)Weffl)[i] = WeffW[base + i];
  if (tid < 256) {
    biasl[tid] = bip[m * 256 + tid] + cbias[m * 256 + tid];
    Hl[tid] = 0.f;
  }
  float xreg = 0.f;
  if (m < 4 && tid < 96) {
    xl[0][tid] = x[((size_t)b * TT + 0) * II + tid];
    xreg       = x[((size_t)b * TT + 1) * II + tid];
  }
  // W_V half-column: w[j] = WV[m][p*128+j][h_out]  (128 VGPR, no spill)
  float w[128];
  #pragma unroll
  for (int j = 0; j < 128; ++j)
    w[j] = WV[((size_t)(m * 256 + p * 128 + j)) * 256 + h_out];
  __syncthreads();
  // inp for t=0
  if (m < 4 && tid < 256) {
    float a = 0.f;
    for (int i = 0; i < cnt; ++i) a += xl[0][xoff + i] * Weffl[i][tid];
    inpl[0][tid] = a;
  }
  __syncthreads();

  for (int t = 0; t < TT; ++t) {
    const int buf = t & 1;
    const int mb12 = (buf * 32 + b) * 12;
    const int qb   = (buf * 32 + b) * 192;

    // x double-buffer: stage x_{t+1}, prefetch x_{t+2}
    if (m < 4 && tid < 96) {
      xl[(t + 1) & 1][tid] = xreg;
      xreg = (t + 2 < TT) ? x[((size_t)b * TT + t + 2) * II + tid] : 0.f;
    }

    // ---- P1: tmpUr[r] = sum_h Hl[h]*U[m][h][r] (16 groups x 32 lanes) ----
    {
      float s = 0.f;
      const float* up = &Utl[g32][0];
      #pragma unroll
      for (int h = l32; h < 256; h += 32) s += Hl[h] * up[h];
      #pragma unroll
      for (int off = 16; off > 0; off >>= 1) s += __shfl_down(s, off, 32);
      if (l32 == 0) tmpUr[g32] = s;
    }
    LBAR();  // B1

    // ---- P2: Hin = tanh(inp + rec + bias) ----
    if (tid < 256) {
      float rec = 0.f;
      #pragma unroll
      for (int r = 0; r < 16; ++r) rec += tmpUr[r] * Vrl[r][tid];
      float inp = (m < 4) ? inpl[buf][tid] : 0.f;
      Hin[tid] = tanhf(inp + rec + biasl[tid]);
    }
    LBAR();  // B2

    // ---- P3: Vc half-dot -> publish from regs; QK -> publish from lanes ----
    float accVc = 0.f;
    {
      const float4* h4 = (const float4*)&Hin[p * 128];
      #pragma unroll
      for (int q = 0; q < 32; ++q) {
        float4 hv = h4[q];
        accVc += hv.x * w[4 * q] + hv.y * w[4 * q + 1]
               + hv.z * w[4 * q + 2] + hv.w * w[4 * q + 3];
      }
      __hip_atomic_store(&VcHG[(mb12 + m * 2 + p) * 256 + h_out], accVc,
                         __ATOMIC_RELAXED, __HIP_MEMORY_SCOPE_SYSTEM);
      if (p == 1) Vcp1[h_out] = accVc;   // own p=1 half for local Acomm
    }
    {
      // 32 groups of 16 lanes: Q rows (g16<16) and K rows (g16>=16)
      const int r = g16 & 15;
      const float* wp = (g16 < 16) ? &WQtl[r][0] : &WKtl[r][0];
      float s = 0.f;
      #pragma unroll
      for (int j = 0; j < 16; ++j) { int h = l16 + 16 * j; s += Hin[h] * wp[h]; }
      s += __shfl_down(s, 8, 16);
      s += __shfl_down(s, 4, 16);
      s += __shfl_down(s, 2, 16);
      s += __shfl_down(s, 1, 16);
      if (l16 == 0)
        __hip_atomic_store(&QKG[qb + ((g16 < 16) ? 0 : 96) + m * 16 + r], s,
                           __ATOMIC_RELAXED, __HIP_MEMORY_SCOPE_SYSTEM);
    }
    asm volatile("s_waitcnt vmcnt(0)" ::: "memory");  // each wave drains its stores
    LBAR();  // B3 — all waves drained
    if (tid == 0)
      __hip_atomic_store(&seqG[b * 16 + m], (unsigned)(t + 1),
                         __ATOMIC_RELAXED, __HIP_MEMORY_SCOPE_SYSTEM);

    // ---- P4: overlap — waves 4-7 compute inp(t+1); wave0 lanes<6 poll ----
    if (tid >= 256 && m < 4) {
      const int h = tid - 256, nb = (t + 1) & 1;
      float a = 0.f;
      for (int i = 0; i < cnt; ++i) a += xl[nb][xoff + i] * Weffl[i][h];
      inpl[nb][h] = a;
    }
    if (w64 == 0 && lane < 6) {
      while (__hip_atomic_load(&seqG[b * 16 + lane],
                               __ATOMIC_RELAXED, __HIP_MEMORY_SCOPE_SYSTEM)
             < (unsigned)(t + 1)) {}
    }
    LBAR();  // B4 — all peers published

    // ---- P5: issue qkl load first, then the 10 remote Vc-half loads ----
    float qv = 0.f;
    if (tid < 192)
      qv = __hip_atomic_load(&QKG[qb + tid],
                             __ATOMIC_RELAXED, __HIP_MEMORY_SCOPE_SYSTEM);
    float vA[6], vB[6];
    if (tid < 256) {
      #pragma unroll
      for (int mm = 0; mm < 6; ++mm) {
        if (mm != m) {
          vA[mm] = __hip_atomic_load(&VcHG[(mb12 + mm * 2 + 0) * 256 + tid],
                                     __ATOMIC_RELAXED, __HIP_MEMORY_SCOPE_SYSTEM);
          vB[mm] = __hip_atomic_load(&VcHG[(mb12 + mm * 2 + 1) * 256 + tid],
                                     __ATOMIC_RELAXED, __HIP_MEMORY_SCOPE_SYSTEM);
        }
      }
    }
    if (tid < 192) qkl[tid] = qv;   // waits only on the qkl load (issued first)
    LBAR();  // B5

    // ---- P6: attention (6 lanes of wave 0) ----
    if (w64 == 0 && lane < 6) {
      float sc[6]; float mx = -1e30f;
      #pragma unroll
      for (int n = 0; n < 6; ++n) {
        float s = 0.f;
        #pragma unroll
        for (int k = 0; k < 16; ++k) s += qkl[lane * 16 + k] * qkl[96 + n * 16 + k];
        sc[n] = s * 0.25f; mx = fmaxf(mx, sc[n]);
      }
      float sm = 0.f;
      #pragma unroll
      for (int n = 0; n < 6; ++n) { sc[n] = expf(sc[n] - mx); sm += sc[n]; }
      float inv = 1.f / sm;
      #pragma unroll
      for (int n = 0; n < 6; ++n) {
        float a = sc[n] * inv;
        attnl[lane * 6 + n] = a;
        if (m == 0) attnO[((size_t)t * 32 + b) * 36 + lane * 6 + n] = a;
      }
    }
    LBAR();  // B6

    // ---- P7: A_comm + H_new ----
    if (tid < 256) {
      vA[m] = accVc;        // this thread's p==0 half? only valid for tid<256 (p=0)
      vB[m] = Vcp1[tid];
      float ac = 0.f;
      #pragma unroll
      for (int mm = 0; mm < 6; ++mm) ac += attnl[mm * 6 + m] * (vA[mm] + vB[mm]);
      float hn = Hin[tid] + ac;
      Hl[tid] = hn;
      size_t gi = (((size_t)t * 32 + b) * 6 + m) * 256 + tid;
      Hseq[gi] = hn;
      Acm[gi]  = ac;
    }
    LBAR();  // B7 — Hl ready; Hseq/Acm stores drain later, off the path
  }
}

// ---------------------------------------------------------------------------
// K3: out[b,t,:] = concat(Hseq[t,b,4,:], Hseq[t,b,5,:]) @ W_out + b_out
// ---------------------------------------------------------------------------
__global__ __launch_bounds__(256) void rim_out(
    const float* __restrict__ Hseq, const float* __restrict__ Wout,
    const float* __restrict__ bout, float* __restrict__ out0)
{
  __shared__ float hrow[4][512];
  const int tid = threadIdx.x;
  const int row0 = blockIdx.x * 4;
  for (int i = tid; i < 4 * 512; i += 256) {
    int r = i >> 9, j = i & 511;
    int rb = row0 + r; int b = rb >> 9, t = rb & 511;
    hrow[r][j] = Hseq[((size_t)(t * 32 + b) * 6 + 4 + (j >> 8)) * 256 + (j & 255)];
  }
  __syncthreads();
  const int r = tid >> 6, o = tid & 63;
  const int rb = row0 + r;
  float s = bout[o];
  const float* hp = hrow[r];
  const float* wp = Wout + o;
  #pragma unroll 8
  for (int j = 0; j < 512; ++j) s += hp[j] * wp[(size_t)j * 64];
  out0[(size_t)rb * 64 + o] = s;
}

// ---------------------------------------------------------------------------
// Fallback (round-1 monolithic loop, one block per batch)
// ---------------------------------------------------------------------------
__global__ __launch_bounds__(512) void rim_loop(
    const float* __restrict__ x,
    const float* __restrict__ Vr, const float* __restrict__ WV,
    const float* __restrict__ Wout, const float* __restrict__ bout,
    const float* __restrict__ bip, const float* __restrict__ cbias,
    const float* __restrict__ Ut, const float* __restrict__ WQt, const float* __restrict__ WKt,
    const float* __restrict__ Weff,
    float* __restrict__ out0, float* __restrict__ Hseq,
    float* __restrict__ Acm, float* __restrict__ attnO)
{
  __shared__ float Hl[6][256];
  __shared__ float Hin[6][256];
  __shared__ float biasl[6][256];
  __shared__ float Vcp[2][6][256];
  __shared__ float tmpUr[6][16];
  __shared__ float Qc[6][16], Kc[6][16];
  __shared__ float attnl[36];
  __shared__ float pout[8][64];
  __shared__ float xl[96];
  __shared__ float inpl[4][256];

  const int b = blockIdx.x;
  const int tid = threadIdx.x;
  const int wid = tid >> 5, lane = tid & 31;

  for (int i = tid; i < 1536; i += 512) {
    int m = i >> 8, h = i & 255;
    biasl[m][h] = bip[i] + cbias[i];
    Hl[m][h] = 0.f;
  }
  __syncthreads();

  for (int t = 0; t < TT; ++t) {
    if (tid < 96) xl[tid] = x[(b * TT + t) * II + tid];
    __syncthreads();
    for (int mh = tid; mh < 1024; mh += 512) {
      int m = mh >> 8, h = mh & 255;
      const int base = (m == 0) ? 0 : (m == 1) ? 8192 : (m == 2) ? 16384 : 32768;
      const int cnt  = (m < 2) ? 32 : 64;
      const int xoff = (m < 2) ? 64 : 0;
      float a = 0.f;
      for (int i = 0; i < cnt; ++i) a += xl[xoff + i] * Weff[base + i * 256 + h];
      inpl[m][h] = a;
    }

    for (int pq = wid; pq < 96; pq += 16) {
      int m = pq >> 4, r = pq & 15;
      const float* up = Ut + (m * 16 + r) * 256;
      float s = 0.f;
      #pragma unroll
      for (int h = lane; h < 256; h += 32) s += Hl[m][h] * up[h];
      #pragma unroll
      for (int off = 16; off > 0; off >>= 1) s += __shfl_down(s, off, 32);
      if (lane == 0) tmpUr[m][r] = s;
    }
    __syncthreads();

    for (int mh = tid; mh < 1536; mh += 512) {
      int m = mh >> 8, h = mh & 255;
      float rec = 0.f;
      const float* vp = Vr + m * 4096 + h;
      #pragma unroll
      for (int r = 0; r < 16; ++r) rec += tmpUr[m][r] * vp[r * 256];
      float pre = (m < 4) ? inpl[m][h] : 0.f;
      Hin[m][h] = tanhf(pre + rec + biasl[m][h]);
    }
    __syncthreads();

    for (int pq = wid; pq < 192; pq += 16) {
      int q = pq % 96;
      int m = q >> 4, k = q & 15;
      const float* wp = ((pq < 96) ? WQt : WKt) + (m * 16 + k) * 256;
      float s = 0.f;
      #pragma unroll
      for (int h = lane; h < 256; h += 32) s += Hin[m][h] * wp[h];
      #pragma unroll
      for (int off = 16; off > 0; off >>= 1) s += __shfl_down(s, off, 32);
      if (lane == 0) { if (pq < 96) Qc[m][k] = s; else Kc[m][k] = s; }
    }

    {
      const int h_out = tid & 255, half = tid >> 8;
      for (int m = 0; m < 6; ++m) {
        const float* wv = WV + ((size_t)(m * 256 + half * 128)) * 256 + h_out;
        const float* hv = &Hin[m][half * 128];
        float s = 0.f;
        #pragma unroll 8
        for (int j = 0; j < 128; ++j) s += hv[j] * wv[(size_t)j * 256];
        Vcp[half][m][h_out] = s;
      }
    }
    __syncthreads();

    if (tid < 36) {
      int m = tid / 6, n = tid % 6;
      float s = 0.f;
      #pragma unroll
      for (int k = 0; k < 16; ++k) s += Qc[m][k] * Kc[n][k];
      attnl[tid] = s * 0.25f;
    }
    __syncthreads();
    if (tid < 6) {
      int m = tid;
      float mx = -1e30f;
      #pragma unroll
      for (int n = 0; n < 6; ++n) mx = fmaxf(mx, attnl[m * 6 + n]);
      float e[6], sm = 0.f;
      #pragma unroll
      for (int n = 0; n < 6; ++n) { e[n] = expf(attnl[m * 6 + n] - mx); sm += e[n]; }
      float inv = 1.f / sm;
      #pragma unroll
      for (int n = 0; n < 6; ++n) attnl[m * 6 + n] = e[n] * inv;
    }
    __syncthreads();
    if (tid < 36) attnO[(size_t)(t * 32 + b) * 36 + tid] = attnl[tid];

    for (int mh = tid; mh < 1536; mh += 512) {
      int n = mh >> 8, h = mh & 255;
      float ac = 0.f;
      #pragma unroll
      for (int m = 0; m < 6; ++m)
        ac += attnl[m * 6 + n] * (Vcp[0][m][h] + Vcp[1][m][h]);
      float hn = Hin[n][h] + ac;
      Hl[n][h] = hn;
      size_t gi = ((size_t)(t * 32 + b) * 6 + n) * 256 + h;
      Hseq[gi] = hn;
      Acm[gi]  = ac;
    }
    __syncthreads();

    {
      const int o = tid & 63, js = tid >> 6;
      const float* hp = &Hl[4][0];
      const float* wp = Wout + (size_t)(js * 64) * 64 + o;
      float s = 0.f;
      #pragma unroll 8
      for (int jj = 0; jj < 64; ++jj) s += hp[js * 64 + jj] * wp[(size_t)jj * 64];
      pout[js][o] = s;
    }
    __syncthreads();
    if (tid < 64) {
      float s = bout[tid];
      #pragma unroll
      for (int js = 0; js < 8; ++js) s += pout[js][tid];
      out0[(size_t)(b * TT + t) * 64 + tid] = s;
    }
  }
}

// ---------------------------------------------------------------------------
extern "C" void kernel_launch(void* const* d_in, const int* in_sizes, int n_in,
                              void* d_out, int out_size, void* d_ws, size_t ws_size,
                              hipStream_t stream) {
  const float* x    = (const float*)d_in[0];
  const float* W_ip = (const float*)d_in[1];
  const float* b_ip = (const float*)d_in[2];
  const float* U    = (const float*)d_in[3];
  const float* Vr   = (const float*)d_in[4];
  const float* cb   = (const float*)d_in[5];
  const float* Wt   = (const float*)d_in[6];
  const float* Wsn  = (const float*)d_in[7];
  const float* WQ   = (const float*)d_in[8];
  const float* WK   = (const float*)d_in[9];
  const float* WV   = (const float*)d_in[10];
  const float* Wo   = (const float*)d_in[11];
  const float* bo   = (const float*)d_in[12];

  float* out  = (float*)d_out;
  float* Hseq = out + O_HSEQ;
  float* Ain  = out + O_AIN;
  float* Acm  = out + O_ACM;
  float* attn = out + O_ATTN;

  float* ws   = (float*)d_ws;
  float* Weff = ws + WS_WEFF;
  float* Ut   = ws + WS_UT;
  float* WQt  = ws + WS_WQT;
  float* WKt  = ws + WS_WKT;

  hipLaunchKernelGGL(rim_weff, dim3(288), dim3(256), 0, stream,
                     Wt, Wsn, W_ip, U, WQ, WK, Weff, Ut, WQt, WKt);
  hipLaunchKernelGGL(rim_pre, dim3(1024), dim3(256), 0, stream,
                     x, Wt, Wsn, Ain);

  if (ws_size >= (size_t)WS_COOP_FLOATS * sizeof(float)) {
    float* VcHG = ws + WS_VCH;
    float* QKG  = ws + WS_QK;
    unsigned int* seqG = (unsigned int*)(ws + WS_FLAG);
    hipMemsetAsync((void*)seqG, 0, 512 * sizeof(unsigned int), stream);

    void* args[] = { (void*)&x, (void*)&Vr, (void*)&WV, (void*)&b_ip, (void*)&cb,
                     (void*)&Ut, (void*)&WQt, (void*)&WKt, (void*)&Weff,
                     (void*)&VcHG, (void*)&QKG, (void*)&seqG,
                     (void*)&Hseq, (void*)&Acm, (void*)&attn };
    hipLaunchCooperativeKernel((void*)rim_step, dim3(192), dim3(512), args, 0, stream);

    hipLaunchKernelGGL(rim_out, dim3(4096), dim3(256), 0, stream,
                       Hseq, Wo, bo, out);
  } else {
    hipLaunchKernelGGL(rim_loop, dim3(32), dim3(512), 0, stream,
                       x, Vr, WV, Wo, bo, b_ip, cb, Ut, WQt, WKt, Weff,
                       out, Hseq, Acm, attn);
  }
}